// Round 9
// baseline (55.435 us; speedup 1.0000x reference)
//
#include <hip/hip_runtime.h>
#include <stdint.h>

#define NB   16
#define CIN  32
#define COUT 32
#define HH   256
#define WW   256
#define HWSZ (HH * WW)
#define EPSV 1e-5f
#define TWD  264     // LDS row words: zero pads at index 3 and 260, data at 4..259
#define NPACKB (NB * HWSZ / 4 / 256)   // 1024 activation-pack blocks

typedef int  v4i  __attribute__((ext_vector_type(4)));
typedef int  v16i __attribute__((ext_vector_type(16)));
typedef unsigned int v4u __attribute__((ext_vector_type(4)));

// ---------------------------------------------------------------------------
// Kernel 1: unified pack kernel.
// Blocks 0..NPACKB-1: binarize + bit-pack activations, one uint32 per
//   (n,h,w): bit c = signbit(x[n,c,h,w]). Each thread packs 4 consecutive
//   words via nontemporal uint4 loads (x is read exactly once device-wide).
// Block NPACKB: weight pack -> MFMA A-fragments + BN/correction tables.
//   afrag[t*64+lane] = 16 i8 (+-1): o = lane&31, ch = (lane>>5)*16 + e
//   c0f[cls*32+o] = beta - mean*inv + Wsum[cls][o]*inv
//   c0f[288+o]    = -2 * gamma/sqrt(var+eps)   (c1, appended)
// With B-bit = signbit(x), pads/invalid taps = 0:
//   conv = Wsum_valid - 2*acc  ->  result = acc*c1 + c0.
// ---------------------------------------------------------------------------
__global__ __launch_bounds__(256) void pack_kernel(
    const uint32_t* __restrict__ x, const float* __restrict__ wt,
    const float* __restrict__ gamma, const float* __restrict__ beta,
    const float* __restrict__ rmean, const float* __restrict__ rvar,
    uint32_t* __restrict__ px, uint4* __restrict__ afrag,
    float* __restrict__ c0f) {
    const int tid = threadIdx.x;
    if (blockIdx.x < NPACKB) {
        // ---- activation pack ----
        const int gt  = blockIdx.x * 256 + tid;   // 0 .. NB*HWSZ/4-1
        const int wi  = gt << 2;                  // packed-word index
        const int n   = wi >> 16;                 // / HWSZ
        const int rem = wi & (HWSZ - 1);          // h*WW + w
        const uint32_t* xp = x + (size_t)n * (CIN * HWSZ) + rem;
        uint32_t b0 = 0, b1 = 0, b2 = 0, b3 = 0;
#pragma unroll
        for (int c = 0; c < CIN; ++c) {
            const v4u v = __builtin_nontemporal_load(
                reinterpret_cast<const v4u*>(xp + (size_t)c * HWSZ));
            b0 |= (v.x >> 31) << c;               // bit = signbit (x < 0)
            b1 |= (v.y >> 31) << c;
            b2 |= (v.z >> 31) << c;
            b3 |= (v.w >> 31) << c;
        }
        *reinterpret_cast<uint4*>(px + wi) = make_uint4(b0, b1, b2, b3);
        return;
    }
    // ---- weight block ----
    __shared__ uint32_t pws[COUT * 9];
#pragma unroll
    for (int it = 0; it < 2; ++it) {
        const int j = tid + it * 256;
        if (j < COUT * 9) {
            const int o = j / 9, t = j % 9;
            uint32_t bits = 0;
#pragma unroll
            for (int c = 0; c < CIN; ++c)
                bits |= (wt[(o * CIN + c) * 9 + t] < 0.f) ? (1u << c) : 0u;  // 1 = -1
            pws[j] = bits;
        }
    }
    __syncthreads();
    if (tid < 64) {
        const int sh = (tid & 32) >> 1;        // channel half 0/16
#pragma unroll
        for (int t = 0; t < 9; ++t) {
            const uint32_t chunk = pws[(tid & 31) * 9 + t] >> sh;
            uint32_t w[4];
#pragma unroll
            for (int k = 0; k < 4; ++k) {
                const uint32_t y = (((chunk >> (4 * k)) & 0xFu) * 0x204081u) & 0x01010101u;
                w[k] = (y * 0xFEu) | 0x01010101u;   // bit? 0xFF(-1) : 0x01(+1)
            }
            afrag[t * 64 + tid] = make_uint4(w[0], w[1], w[2], w[3]);
        }
    }
#pragma unroll
    for (int it = 0; it < 2; ++it) {
        const int j = tid + it * 256;
        if (j < 9 * COUT) {
            const int cls = j >> 5;            // 0..8
            const int o   = j & 31;
            const int rc = cls / 3, cc = cls % 3;
            int wsum = 0;
#pragma unroll
            for (int dh = 0; dh < 3; ++dh)
#pragma unroll
                for (int dw = 0; dw < 3; ++dw) {
                    const bool bad = (rc == 0 && dh == 0) || (rc == 2 && dh == 2) ||
                                     (cc == 0 && dw == 0) || (cc == 2 && dw == 2);
                    if (!bad) wsum += 32 - 2 * __popc(pws[o * 9 + dh * 3 + dw]);
                }
            const float inv = gamma[o] * rsqrtf(rvar[o] + EPSV);
            c0f[cls * 32 + o] = beta[o] - rmean[o] * inv + (float)wsum * inv;
            if (cls == 0) c0f[288 + o] = -2.0f * inv;
        }
    }
}

// ---------------------------------------------------------------------------
// Kernel 2: implicit-GEMM i8-MFMA conv + BN + ReLU, reading pre-packed px.
// Round-8 conv structure unchanged; only the staging source differs: the
// 4 halo rows come from px (L2/L3-resident, 4 KB/block) instead of being
// packed from x. Block = (n, 2 output rows): 2048 blocks, 512 threads.
// Threads 0..255 stage the 4 px rows (1 uint4 each); threads 256..511 stage
// A-fragments + BN tables into LDS. Conv: 8 waves, wave = (row = wave>>2,
// 64-px segment = wave&3), 2-accumulator tap-outer inner loop.
// ---------------------------------------------------------------------------
__global__ __launch_bounds__(512) void biconv_mfma(
    const uint32_t* __restrict__ px, const uint4* __restrict__ afrag,
    const float* __restrict__ c0f, float* __restrict__ out) {
    const uint32_t bid = blockIdx.x;                       // 0..2047
    const uint32_t wg  = ((bid & 7u) << 8) | (bid >> 3);   // bijective XCD chunk
    const int n   = wg >> 7;                               // 0..15
    const int h0  = (wg & 127) << 1;                       // 0,2,...,254
    const int tid  = threadIdx.x;
    const int lane = tid & 63;
    const int wave = tid >> 6;

    __shared__ uint32_t tiles[4][TWD];
    __shared__ uint4    afsh[9 * 64];     // 9216 B
    __shared__ float    csh[320];         // c0[0..287], c1[288..319]

    if (tid < 256) {
        // ---- stage 4 px rows: r = tid>>6, quad q = tid&63 ----
        const int r  = tid >> 6;
        const int q  = tid & 63;
        const int hr = h0 - 1 + r;                // -1 .. 256
        uint4 v = make_uint4(0u, 0u, 0u, 0u);
        if (hr >= 0 && hr < HH)
            v = *reinterpret_cast<const uint4*>(px + (size_t)n * HWSZ + (size_t)hr * WW + (q << 2));
        *reinterpret_cast<uint4*>(&tiles[r][(q << 2) + 4]) = v;
    } else {
        const int t2 = tid - 256;          // 0..255
        afsh[t2]       = afrag[t2];
        afsh[t2 + 256] = afrag[t2 + 256];
        if (t2 < 64)  afsh[t2 + 512] = afrag[t2 + 512];    // 576 total
        csh[t2] = c0f[t2];
        if (t2 < 64)  csh[t2 + 256] = c0f[t2 + 256];       // 320 total
        if (t2 < 8)   tiles[t2 >> 1][(t2 & 1) ? 260 : 3] = 0u;
    }
    __syncthreads();

    // ---- conv: wave = (row rsel, 64-px segment); 2 accumulator tiles ----
    const int l31  = lane & 31;
    const int shv  = (lane & 32) >> 1;     // channel half for B expansion
    const int og   = (lane >> 5) << 2;     // C/D row offset 0/4
    const int rsel = wave >> 2;            // output row within pair: 0/1
    const int pA   = ((wave & 3) << 6) + l31;   // tile A pixel
    const int pB   = pA + 32;                   // tile B pixel

    const int h  = h0 + rsel;
    const int rc = (h == 0) ? 0 : ((h == HH - 1) ? 2 : 1);

    v16i acc0 = {0}, acc1 = {0};
#pragma unroll
    for (int dh = 0; dh < 3; ++dh) {
        const uint32_t* trow = &tiles[rsel + dh][0];
#pragma unroll
        for (int dw = 0; dw < 3; ++dw) {
            const v4i a = *reinterpret_cast<const v4i*>(&afsh[(dh * 3 + dw) * 64 + lane]);
            const uint32_t hA = trow[pA + 3 + dw] >> shv;
            const uint32_t hB = trow[pB + 3 + dw] >> shv;
            v4i b;
            b.x = (int)((( hA        & 0xFu) * 0x204081u) & 0x01010101u);
            b.y = (int)((((hA >> 4)  & 0xFu) * 0x204081u) & 0x01010101u);
            b.z = (int)((((hA >> 8)  & 0xFu) * 0x204081u) & 0x01010101u);
            b.w = (int)((((hA >> 12) & 0xFu) * 0x204081u) & 0x01010101u);
            acc0 = __builtin_amdgcn_mfma_i32_32x32x32_i8(a, b, acc0, 0, 0, 0);
            b.x = (int)((( hB        & 0xFu) * 0x204081u) & 0x01010101u);
            b.y = (int)((((hB >> 4)  & 0xFu) * 0x204081u) & 0x01010101u);
            b.z = (int)((((hB >> 8)  & 0xFu) * 0x204081u) & 0x01010101u);
            b.w = (int)((((hB >> 12) & 0xFu) * 0x204081u) & 0x01010101u);
            acc1 = __builtin_amdgcn_mfma_i32_32x32x32_i8(a, b, acc1, 0, 0, 0);
        }
    }

    // ---- epilogue: C/D row = (e&3)+8*(e>>2)+og, col = pixel ----
    const int ccA = (pA == 0) ? 0 : ((pA == WW - 1) ? 2 : 1);
    const int ccB = (pB == WW - 1) ? 2 : 1;       // pB >= 32, never 0
    const float* c0A = &csh[(rc * 3 + ccA) * 32];
    const float* c0B = &csh[(rc * 3 + ccB) * 32];
    const float* c1  = &csh[288];
    float* outn = out + (size_t)n * (COUT * HWSZ) + (size_t)h * WW;
#pragma unroll
    for (int e = 0; e < 16; ++e) {
        const int o = (e & 3) + ((e >> 2) << 3) + og;
        const float vA = fmaf((float)acc0[e], c1[o], c0A[o]);
        const float vB = fmaf((float)acc1[e], c1[o], c0B[o]);
        __builtin_nontemporal_store(vA > 0.f ? vA : 0.f, outn + (size_t)o * HWSZ + pA);
        __builtin_nontemporal_store(vB > 0.f ? vB : 0.f, outn + (size_t)o * HWSZ + pB);
    }
}

// ---------------------------------------------------------------------------
extern "C" void kernel_launch(void* const* d_in, const int* in_sizes, int n_in,
                              void* d_out, int out_size, void* d_ws, size_t ws_size,
                              hipStream_t stream) {
    const float* x     = (const float*)d_in[0];
    const float* wt    = (const float*)d_in[1];
    const float* gamma = (const float*)d_in[2];
    const float* beta  = (const float*)d_in[3];
    const float* rmean = (const float*)d_in[4];
    const float* rvar  = (const float*)d_in[5];
    float* out = (float*)d_out;

    uint32_t* pxbuf = (uint32_t*)d_ws;                       // 4 MB
    uint4*    afrag = (uint4*)(pxbuf + (size_t)NB * HWSZ);   // 9216 B
    float*    c0f   = (float*)((char*)afrag + 9216);         // 288 + 32 floats

    pack_kernel<<<dim3(NPACKB + 1), dim3(256), 0, stream>>>(
        (const uint32_t*)x, wt, gamma, beta, rmean, rvar, pxbuf, afrag, c0f);
    biconv_mfma<<<dim3(NB * HH / 2), dim3(512), 0, stream>>>(
        pxbuf, afrag, c0f, out);
}